// Round 7
// baseline (530.578 us; speedup 1.0000x reference)
//
#include <hip/hip_runtime.h>
#include <hip/hip_bf16.h>

constexpr int N   = 50000;
constexpr int E   = 1600000;
constexpr int C   = 128;             // channels (H * 32)
constexpr int H   = 4;               // heads
constexpr float NEG  = 0.2f;
constexpr float SEPS = 1e-16f;
constexpr float LEPS = 1e-5f;

// K1: h = x @ W (f32), fused attention dots a_s = <h_nh, att_src_h>, a_d likewise.
__global__ __launch_bounds__(128) void k1_gemm(
    const float* __restrict__ x, const float* __restrict__ W,
    const float* __restrict__ att_s, const float* __restrict__ att_d,
    float* __restrict__ h, float* __restrict__ as_, float* __restrict__ ad_)
{
    const int n = blockIdx.x;
    const int t = threadIdx.x;           // output channel = head*32 + c
    __shared__ float xs[C];
    xs[t] = x[n * C + t];
    __syncthreads();
    float acc = 0.f;
#pragma unroll 16
    for (int k = 0; k < C; ++k)
        acc = fmaf(xs[k], W[k * C + t], acc);
    h[(size_t)n * C + t] = acc;
    float vs = acc * att_s[t];
    float vd = acc * att_d[t];
#pragma unroll
    for (int off = 16; off; off >>= 1) {   // reduce within each 32-lane head group
        vs += __shfl_xor(vs, off, 64);
        vd += __shfl_xor(vd, off, 64);
    }
    if ((t & 31) == 0) {
        as_[n * H + (t >> 5)] = vs;
        ad_[n * H + (t >> 5)] = vd;
    }
}

// KA: in-degree count per destination (self-loops handled analytically in KD).
__global__ __launch_bounds__(256) void ka_count(
    const int* __restrict__ ei, int* __restrict__ cnt)
{
    int e = blockIdx.x * blockDim.x + threadIdx.x;
    if (e >= E) return;
    atomicAdd(cnt + ei[E + e], 1);
}

// KB: exclusive prefix scan cnt[N] -> row_ptr[N+1]. Single block, 1024 threads.
__global__ __launch_bounds__(1024) void kb_scan(
    const int* __restrict__ cnt, int* __restrict__ row_ptr)
{
    __shared__ int wave_tot[16];
    __shared__ int carry;
    const int t = threadIdx.x;
    const int wave = t >> 6, lane = t & 63;
    if (t == 0) carry = 0;
    __syncthreads();
    for (int base = 0; base < N; base += 1024) {
        int i = base + t;
        int orig = (i < N) ? cnt[i] : 0;
        int v = orig;
#pragma unroll
        for (int off = 1; off < 64; off <<= 1) {
            int u = __shfl_up(v, off, 64);
            if (lane >= off) v += u;
        }
        if (lane == 63) wave_tot[wave] = v;
        __syncthreads();
        if (t < 16) {
            int w = wave_tot[t];
#pragma unroll
            for (int off = 1; off < 16; off <<= 1) {
                int u = __shfl_up(w, off, 64);
                if (t >= off) w += u;
            }
            wave_tot[t] = w;   // inclusive scan of wave totals
        }
        __syncthreads();
        int add = carry + (wave ? wave_tot[wave - 1] : 0);
        if (i < N) row_ptr[i] = v + add - orig;   // exclusive
        __syncthreads();
        if (t == 0) carry += wave_tot[15];
        __syncthreads();
    }
    if (t == 0) row_ptr[N] = carry;
}

// KC: scatter sources into CSR buckets (order within bucket irrelevant).
__global__ __launch_bounds__(256) void kc_fill(
    const int* __restrict__ ei, const int* __restrict__ row_ptr,
    int* __restrict__ cursor, int* __restrict__ col)
{
    int e = blockIdx.x * blockDim.x + threadIdx.x;
    if (e >= E) return;
    int src = ei[e], dst = ei[E + e];
    int pos = atomicAdd(cursor + dst, 1);
    col[row_ptr[dst] + pos] = src;
}

// KD: fused attention-softmax aggregation + bias + LayerNorm + ELU -> f32 out.
// One 64-lane wave per node, 2 channels per lane. No segment-max needed:
// |logits| <~ 6 so exp stays in range; alpha normalization folds into one divide.
__global__ __launch_bounds__(256) void kd_agg_ln(
    const int* __restrict__ row_ptr, const int* __restrict__ col,
    const float* __restrict__ h, const float* __restrict__ as_,
    const float* __restrict__ ad_,
    const float* __restrict__ bias, const float* __restrict__ gamma,
    const float* __restrict__ beta, float* __restrict__ out)
{
    int gid = blockIdx.x * blockDim.x + threadIdx.x;
    int n = gid >> 6;
    if (n >= N) return;
    const int lane = gid & 63;
    const int c0 = lane * 2;
    const int head = lane >> 4;

    const float adn = ad_[n * H + head];
    // self-loop term (src == dst == n)
    float l = as_[n * H + head] + adn;
    l = l > 0.f ? l : NEG * l;
    float w = __expf(l);
    float den = w;
    float2 hv = *(const float2*)(h + (size_t)n * C + c0);
    float num0 = w * hv.x;
    float num1 = w * hv.y;

    const int beg = row_ptr[n], end = row_ptr[n + 1];
    int src_next = (beg < end) ? col[beg] : 0;
    for (int k = beg; k < end; ++k) {
        int src = src_next;
        if (k + 1 < end) src_next = col[k + 1];
        float l2 = as_[src * H + head] + adn;
        l2 = l2 > 0.f ? l2 : NEG * l2;
        float w2 = __expf(l2);
        den += w2;
        hv = *(const float2*)(h + (size_t)src * C + c0);
        num0 = fmaf(w2, hv.x, num0);
        num1 = fmaf(w2, hv.y, num1);
    }

    float inv_den = 1.f / (den + SEPS);
    float v0 = num0 * inv_den + bias[c0];
    float v1 = num1 * inv_den + bias[c0 + 1];

    float sum = v0 + v1;
#pragma unroll
    for (int off = 32; off; off >>= 1) sum += __shfl_xor(sum, off, 64);
    float mu = sum * (1.0f / C);
    float d0 = v0 - mu, d1 = v1 - mu;
    float sq = d0 * d0 + d1 * d1;
#pragma unroll
    for (int off = 32; off; off >>= 1) sq += __shfl_xor(sq, off, 64);
    float inv = rsqrtf(sq * (1.0f / C) + LEPS);
    float y0 = d0 * inv * gamma[c0]     + beta[c0];
    float y1 = d1 * inv * gamma[c0 + 1] + beta[c0 + 1];
    y0 = y0 > 0.f ? y0 : __expf(y0) - 1.f;
    y1 = y1 > 0.f ? y1 : __expf(y1) - 1.f;
    float2 o; o.x = y0; o.y = y1;
    *(float2*)(out + (size_t)n * C + c0) = o;   // f32 output — reference dtype
}

extern "C" void kernel_launch(void* const* d_in, const int* in_sizes, int n_in,
                              void* d_out, int out_size, void* d_ws, size_t ws_size,
                              hipStream_t stream)
{
    const float* x     = (const float*)d_in[0];
    const int*   ei    = (const int*)  d_in[1];
    const float* W     = (const float*)d_in[2];
    const float* att_s = (const float*)d_in[3];
    const float* att_d = (const float*)d_in[4];
    const float* bias  = (const float*)d_in[5];
    const float* gamma = (const float*)d_in[6];
    const float* beta  = (const float*)d_in[7];
    float* out = (float*)d_out;

    // ws (~34 MB): h f32[N*C] | as_ f32[N*H] | ad_ f32[N*H] | col int[E]
    //            | row_ptr int[N+1] | cnt int[N]
    char* p = (char*)d_ws;
    float* h       = (float*)p;  p += (size_t)N * C * sizeof(float);
    float* as_     = (float*)p;  p += (size_t)N * H * sizeof(float);
    float* ad_     = (float*)p;  p += (size_t)N * H * sizeof(float);
    int*   col     = (int*)p;    p += (size_t)E * sizeof(int);
    int*   row_ptr = (int*)p;    p += ((size_t)(N + 1) * sizeof(int) + 15) & ~(size_t)15;
    int*   cnt     = (int*)p;

    hipMemsetAsync(cnt, 0, (size_t)N * sizeof(int), stream);
    k1_gemm<<<N, 128, 0, stream>>>(x, W, att_s, att_d, h, as_, ad_);
    ka_count<<<(E + 255) / 256, 256, 0, stream>>>(ei, cnt);
    kb_scan<<<1, 1024, 0, stream>>>(cnt, row_ptr);
    hipMemsetAsync(cnt, 0, (size_t)N * sizeof(int), stream);   // reuse as cursor
    kc_fill<<<(E + 255) / 256, 256, 0, stream>>>(ei, row_ptr, cnt, col);
    kd_agg_ln<<<(N * 64) / 256, 256, 0, stream>>>(
        row_ptr, col, h, as_, ad_, bias, gamma, beta, out);
}

// Round 8
// 369.165 us; speedup vs baseline: 1.4372x; 1.4372x over previous
//
#include <hip/hip_runtime.h>
#include <hip/hip_bf16.h>

typedef __hip_bfloat16 bf16;
typedef unsigned int u32;

constexpr int N   = 50000;
constexpr int E   = 1600000;
constexpr int C   = 128;             // channels (H * 32)
constexpr int H   = 4;               // heads
constexpr float NEG  = 0.2f;
constexpr float SEPS = 1e-16f;
constexpr float LEPS = 1e-5f;

__device__ __forceinline__ float lo16(u32 v) { return __uint_as_float(v << 16); }
__device__ __forceinline__ float hi16(u32 v) { return __uint_as_float(v & 0xFFFF0000u); }

// K1: h = x @ W, 16 nodes per block. x tile in LDS; W read from global (L1-hot,
// traffic /16 vs 1-node-per-block). h stored bf16. Fused att dots.
__global__ __launch_bounds__(256) void k1_gemm(
    const float* __restrict__ x, const float* __restrict__ W,
    const float* __restrict__ att_s, const float* __restrict__ att_d,
    bf16* __restrict__ hb, float* __restrict__ as_, float* __restrict__ ad_)
{
    const int nb = blockIdx.x * 16;
    const int t  = threadIdx.x;
    __shared__ float sx[16 * 128];
    const float4* xg = (const float4*)(x + nb * 128);
    ((float4*)sx)[t]       = xg[t];
    ((float4*)sx)[t + 256] = xg[t + 256];
    __syncthreads();

    const int c = t & 127;           // output channel
    const int g = t >> 7;            // node group (0/1) of 8 nodes
    const float* xb = sx + (g << 10);   // g*8*128
    float acc[8] = {0.f, 0.f, 0.f, 0.f, 0.f, 0.f, 0.f, 0.f};

    for (int k = 0; k < 128; k += 4) {
        const float w0 = W[(k + 0) * 128 + c];
        const float w1 = W[(k + 1) * 128 + c];
        const float w2 = W[(k + 2) * 128 + c];
        const float w3 = W[(k + 3) * 128 + c];
#pragma unroll
        for (int j = 0; j < 8; ++j) {
            const float4 xv = *(const float4*)(xb + j * 128 + k);
            acc[j] = fmaf(xv.x, w0, fmaf(xv.y, w1, fmaf(xv.z, w2, fmaf(xv.w, w3, acc[j]))));
        }
    }

    const int lane = t & 63;
    const int head = c >> 5;
    const float asc = att_s[c], adc = att_d[c];
#pragma unroll
    for (int j = 0; j < 8; ++j) {
        const int node = nb + (g << 3) + j;
        hb[node * 128 + c] = __float2bfloat16(acc[j]);
        float vs = acc[j] * asc;
        float vd = acc[j] * adc;
#pragma unroll
        for (int off = 16; off; off >>= 1) {   // reduce over the 32-lane head group
            vs += __shfl_xor(vs, off, 64);
            vd += __shfl_xor(vd, off, 64);
        }
        if ((lane & 31) == 0) {
            as_[node * H + head] = vs;
            ad_[node * H + head] = vd;
        }
    }
}

// KA: in-degree count per destination (self-loops handled analytically in KD).
__global__ __launch_bounds__(256) void ka_count(
    const int* __restrict__ ei, int* __restrict__ cnt)
{
    int e = blockIdx.x * blockDim.x + threadIdx.x;
    if (e >= E) return;
    atomicAdd(cnt + ei[E + e], 1);
}

// KS1: per-block (1024-wide) exclusive scan of cnt -> row_ptr (local), block sums.
__global__ __launch_bounds__(1024) void ks1(
    const int* __restrict__ cnt, int* __restrict__ row_ptr, int* __restrict__ bsum)
{
    __shared__ int wt[16];
    const int t = threadIdx.x;
    const int wave = t >> 6, lane = t & 63;
    const int i = blockIdx.x * 1024 + t;
    int v = (i < N) ? cnt[i] : 0;
    int incl = v;
#pragma unroll
    for (int off = 1; off < 64; off <<= 1) {
        int u = __shfl_up(incl, off, 64);
        if (lane >= off) incl += u;
    }
    if (lane == 63) wt[wave] = incl;
    __syncthreads();
    if (t < 16) {
        int w = wt[t];
#pragma unroll
        for (int off = 1; off < 16; off <<= 1) {
            int u = __shfl_up(w, off, 64);
            if (t >= off) w += u;
        }
        wt[t] = w;
    }
    __syncthreads();
    int base = wave ? wt[wave - 1] : 0;
    if (i < N) row_ptr[i] = base + incl - v;     // block-local exclusive
    if (t == 1023) bsum[blockIdx.x] = wt[15];
}

// KS2: exclusive scan of the 49 block sums (one wave).
__global__ __launch_bounds__(64) void ks2(int* __restrict__ bsum, int* __restrict__ boff)
{
    const int t = threadIdx.x;
    int v = (t < 49) ? bsum[t] : 0;
    int incl = v;
#pragma unroll
    for (int off = 1; off < 64; off <<= 1) {
        int u = __shfl_up(incl, off, 64);
        if (t >= off) incl += u;
    }
    boff[t] = incl - v;
}

// KS3: add block offsets in place; set row_ptr[N] = E.
__global__ __launch_bounds__(1024) void ks3(
    int* __restrict__ row_ptr, const int* __restrict__ boff)
{
    const int i = blockIdx.x * 1024 + threadIdx.x;
    if (i < N && blockIdx.x > 0) row_ptr[i] += boff[blockIdx.x];
    if (i == 0) row_ptr[N] = E;
}

// KC: scatter sources into CSR buckets; cnt doubles as a countdown cursor.
__global__ __launch_bounds__(256) void kc_fill(
    const int* __restrict__ ei, const int* __restrict__ row_ptr,
    int* __restrict__ cnt, int* __restrict__ col)
{
    int e = blockIdx.x * blockDim.x + threadIdx.x;
    if (e >= E) return;
    int src = ei[e], dst = ei[E + e];
    int pos = atomicSub(cnt + dst, 1) - 1;
    col[row_ptr[dst] + pos] = src;
}

// KD: fused attention-softmax aggregation + bias + LayerNorm + ELU -> f32 out.
// One wave per node, bf16 h (half the gather bytes), group-of-4 edges for MLP.
__global__ __launch_bounds__(256) void kd_agg_ln(
    const int* __restrict__ row_ptr, const int* __restrict__ col,
    const u32* __restrict__ hb, const float* __restrict__ as_,
    const float* __restrict__ ad_,
    const float* __restrict__ bias, const float* __restrict__ gamma,
    const float* __restrict__ beta, float* __restrict__ out)
{
    int gid = blockIdx.x * blockDim.x + threadIdx.x;
    int n = gid >> 6;
    if (n >= N) return;
    const int lane = gid & 63;
    const int head = lane >> 4;

    const float adn = ad_[n * H + head];
    // self-loop term (src == dst == n)
    float l = as_[n * H + head] + adn;
    l = fmaxf(l, NEG * l);
    float w = __expf(l);
    float den = w;
    u32 hv = hb[n * 64 + lane];
    float num0 = w * lo16(hv);
    float num1 = w * hi16(hv);

    int k = row_ptr[n];
    const int end = row_ptr[n + 1];
    for (; k + 4 <= end; k += 4) {
        const int s0 = col[k], s1 = col[k + 1], s2 = col[k + 2], s3 = col[k + 3];
        float l0 = as_[s0 * H + head] + adn;
        float l1 = as_[s1 * H + head] + adn;
        float l2 = as_[s2 * H + head] + adn;
        float l3 = as_[s3 * H + head] + adn;
        const u32 v0 = hb[s0 * 64 + lane];
        const u32 v1 = hb[s1 * 64 + lane];
        const u32 v2 = hb[s2 * 64 + lane];
        const u32 v3 = hb[s3 * 64 + lane];
        l0 = fmaxf(l0, NEG * l0); l1 = fmaxf(l1, NEG * l1);
        l2 = fmaxf(l2, NEG * l2); l3 = fmaxf(l3, NEG * l3);
        const float w0 = __expf(l0), w1 = __expf(l1);
        const float w2 = __expf(l2), w3 = __expf(l3);
        den += (w0 + w1) + (w2 + w3);
        num0 = fmaf(w0, lo16(v0), num0); num1 = fmaf(w0, hi16(v0), num1);
        num0 = fmaf(w1, lo16(v1), num0); num1 = fmaf(w1, hi16(v1), num1);
        num0 = fmaf(w2, lo16(v2), num0); num1 = fmaf(w2, hi16(v2), num1);
        num0 = fmaf(w3, lo16(v3), num0); num1 = fmaf(w3, hi16(v3), num1);
    }
    for (; k < end; ++k) {
        const int s = col[k];
        float ls = as_[s * H + head] + adn;
        ls = fmaxf(ls, NEG * ls);
        const float ws = __expf(ls);
        const u32 vs = hb[s * 64 + lane];
        den += ws;
        num0 = fmaf(ws, lo16(vs), num0);
        num1 = fmaf(ws, hi16(vs), num1);
    }

    const int c0 = lane * 2;
    const float inv_den = 1.f / (den + SEPS);
    float v0 = num0 * inv_den + bias[c0];
    float v1 = num1 * inv_den + bias[c0 + 1];

    float sum = v0 + v1;
#pragma unroll
    for (int off = 32; off; off >>= 1) sum += __shfl_xor(sum, off, 64);
    const float mu = sum * (1.0f / C);
    const float d0 = v0 - mu, d1 = v1 - mu;
    float sq = d0 * d0 + d1 * d1;
#pragma unroll
    for (int off = 32; off; off >>= 1) sq += __shfl_xor(sq, off, 64);
    const float inv = rsqrtf(sq * (1.0f / C) + LEPS);
    float y0 = d0 * inv * gamma[c0]     + beta[c0];
    float y1 = d1 * inv * gamma[c0 + 1] + beta[c0 + 1];
    y0 = y0 > 0.f ? y0 : __expf(y0) - 1.f;
    y1 = y1 > 0.f ? y1 : __expf(y1) - 1.f;
    float2 o; o.x = y0; o.y = y1;
    *(float2*)(out + (size_t)n * C + c0) = o;
}

extern "C" void kernel_launch(void* const* d_in, const int* in_sizes, int n_in,
                              void* d_out, int out_size, void* d_ws, size_t ws_size,
                              hipStream_t stream)
{
    const float* x     = (const float*)d_in[0];
    const int*   ei    = (const int*)  d_in[1];
    const float* W     = (const float*)d_in[2];
    const float* att_s = (const float*)d_in[3];
    const float* att_d = (const float*)d_in[4];
    const float* bias  = (const float*)d_in[5];
    const float* gamma = (const float*)d_in[6];
    const float* beta  = (const float*)d_in[7];
    float* out = (float*)d_out;

    // ws (~21 MB): hb bf16[N*C] | as_ f32[N*H] | ad_ f32[N*H] | col int[E+8]
    //            | row_ptr int[N+1] | cnt int[N] | bsum int[64] | boff int[64]
    char* p = (char*)d_ws;
    bf16*  hb      = (bf16*)p;   p += (size_t)N * C * sizeof(bf16);
    float* as_     = (float*)p;  p += (size_t)N * H * sizeof(float);
    float* ad_     = (float*)p;  p += (size_t)N * H * sizeof(float);
    int*   col     = (int*)p;    p += (size_t)(E + 8) * sizeof(int);
    int*   row_ptr = (int*)p;    p += ((size_t)(N + 1) * sizeof(int) + 15) & ~(size_t)15;
    int*   cnt     = (int*)p;    p += (size_t)N * sizeof(int);
    int*   bsum    = (int*)p;    p += 64 * sizeof(int);
    int*   boff    = (int*)p;

    hipMemsetAsync(cnt, 0, (size_t)N * sizeof(int), stream);
    k1_gemm<<<N / 16, 256, 0, stream>>>(x, W, att_s, att_d, hb, as_, ad_);
    ka_count<<<(E + 255) / 256, 256, 0, stream>>>(ei, cnt);
    ks1<<<(N + 1023) / 1024, 1024, 0, stream>>>(cnt, row_ptr, bsum);
    ks2<<<1, 64, 0, stream>>>(bsum, boff);
    ks3<<<(N + 1023) / 1024, 1024, 0, stream>>>(row_ptr, boff);
    kc_fill<<<(E + 255) / 256, 256, 0, stream>>>(ei, row_ptr, cnt, col);
    kd_agg_ln<<<(N * 64) / 256, 256, 0, stream>>>(
        row_ptr, col, (const u32*)hb, as_, ad_, bias, gamma, beta, out);
}